// Round 18
// baseline (124.709 us; speedup 1.0000x reference)
//
#include <hip/hip_runtime.h>
#include <math.h>

#define BB 8
#define AA 19248
#define GG 32
#define CC 81
#define PP 32
#define PHW 19044   /* 138*138 */
#define KPOS 128
#define NEGRATIO 3
#define NWCH 304    /* 19 outer iters x 16 waves of 64 anchors */
#define NB1 76      /* match-role blocks per image = ceil(AA/256) */
#define NB0 75      /* prep-role blocks per image = ceil(PHW/256) */
#define NPT 1191    /* pixel tiles of 16 = ceil(PHW/16) */
#define NB7 298     /* k7-role blocks per image = ceil(NPT/4) */
#define NB45 24     /* k45-role blocks per image (256 threads each) */
#define NTOT ((NB45 + NB7) * BB)   /* total k457 blocks */

typedef _Float16 half8 __attribute__((ext_vector_type(8)));
typedef float floatx4 __attribute__((ext_vector_type(4)));

// ---------------------------------------------------------------------------
// IoU helper — contraction off so every recomputation produces bitwise-
// identical values and FMA fusion can't flip threshold/argmax decisions.
// ---------------------------------------------------------------------------
__device__ __forceinline__ float iou_one(float ax1, float ay1, float ax2, float ay2,
                                         float areaA,
                                         float gx1, float gy1, float gx2, float gy2) {
#pragma clang fp contract(off)
    float ix1 = fmaxf(ax1, gx1), iy1 = fmaxf(ay1, gy1);
    float ix2 = fminf(ax2, gx2), iy2 = fminf(ay2, gy2);
    float iw = fmaxf(ix2 - ix1, 0.0f), ih = fmaxf(iy2 - iy1, 0.0f);
    float inter = iw * ih;
    float areaB = (gx2 - gx1) * (gy2 - gy1);
    float u = areaA + areaB - inter;
    u = fmaxf(u, 1e-6f);
    return inter / u;
}

// ---------------------------------------------------------------------------
// K01: FUSED prep + match.
//   blockIdx.x <  NB1 : match role — best_key[b][a] = (iou_bits<<6)|(31-g)
//                       (single u64 carries both outputs) + per-(b,g)
//                       best-anchor partial keys.
//   blockIdx.x >= NB1 : prep role — pack binary gt-masks into u32 +
//                       transpose protos to [b][px][32] f16.
// ---------------------------------------------------------------------------
__global__ __launch_bounds__(256) void k01(
    const float* __restrict__ anchors, const float* __restrict__ gt_boxes,
    const float* __restrict__ protos, const float* __restrict__ gtm,
    unsigned long long* __restrict__ best_key,
    unsigned long long* __restrict__ gkey_part, float* __restrict__ acc,
    _Float16* __restrict__ protoT, unsigned* __restrict__ pmask) {
#pragma clang fp contract(off)
    int b = blockIdx.y;
    __shared__ float sg[GG][4];
    __shared__ unsigned long long s_gk[GG];

    if (blockIdx.x >= NB1) {
        // ---- prep role ----
        int px = (blockIdx.x - NB1) * 256 + threadIdx.x;
        if (px >= PHW) return;
        const float* pb = protos + (size_t)b * PP * PHW + px;
        _Float16 v[PP];
        #pragma unroll
        for (int k = 0; k < PP; ++k)
            v[k] = (_Float16)pb[(size_t)k * PHW];
        half8* dst = (half8*)&protoT[((size_t)b * PHW + px) * PP];
        #pragma unroll
        for (int q = 0; q < 4; ++q)
            dst[q] = *(half8*)&v[q * 8];
        const float* gb = gtm + (size_t)b * GG * PHW + px;
        unsigned m = 0u;
        #pragma unroll
        for (int g = 0; g < GG; ++g)
            m |= (gb[(size_t)g * PHW] > 0.5f) ? (1u << g) : 0u;
        pmask[(size_t)b * PHW + px] = m;
        return;
    }

    // ---- match role ----
    int a = blockIdx.x * 256 + threadIdx.x;
    int lane = threadIdx.x & 63;
    if (blockIdx.x == 0 && b == 0 && threadIdx.x < 4)
        ((int*)acc)[threadIdx.x] = 0;            // zero [., ., ., npos]
    for (int t = threadIdx.x; t < GG * 4; t += 256)
        sg[t >> 2][t & 3] = gt_boxes[b * GG * 4 + t] / 550.0f;
    if (threadIdx.x < GG) s_gk[threadIdx.x] = 0ULL;
    __syncthreads();
    bool valid = a < AA;
    int ac = valid ? a : AA - 1;
    float4 an = ((const float4*)anchors)[ac];
    float ax1 = an.x - an.z * 0.5f, ay1 = an.y - an.w * 0.5f;
    float ax2 = an.x + an.z * 0.5f, ay2 = an.y + an.w * 0.5f;
    float areaA = (ax2 - ax1) * (ay2 - ay1);
    unsigned long long bk = 0ULL;   // (vbits<<6)|(31-g): max => first-max argmax
    for (int gg = 0; gg < GG; ++gg) {
        int g = (gg + lane) & (GG - 1);          // stagger: 32 distinct LDS slots
        float v = iou_one(ax1, ay1, ax2, ay2, areaA, sg[g][0], sg[g][1], sg[g][2], sg[g][3]);
        unsigned vb = __float_as_uint(v);        // v >= 0 -> order-preserving
        unsigned long long k2 = ((unsigned long long)vb << 6) | (unsigned)(GG - 1 - g);
        if (k2 > bk) bk = k2;
        if (valid) {
            unsigned long long kg =
                ((unsigned long long)vb << 32) | (unsigned)(AA - 1 - a);
            atomicMax(&s_gk[g], kg);
        }
    }
    if (valid) best_key[(size_t)b * AA + a] = bk;
    __syncthreads();
    if (threadIdx.x < GG)
        gkey_part[((size_t)b * NB1 + blockIdx.x) * GG + threadIdx.x] = s_gk[threadIdx.x];
}

// ---------------------------------------------------------------------------
// K36: FUSED k3 (match-scan) + k6 (top-K radix select), one block per image.
// All per-anchor state (override g, matched g) lives in LDS; the only global
// side products are pos_key (consumed in-block + padded coeff gather),
// act_list (packed a|g<<15|lbl<<20|pos<<31), pos/act counts, and the
// f16 coeff + sel_g tables for K7. Also zeroes the k457 done-counter.
// ---------------------------------------------------------------------------
__global__ __launch_bounds__(1024) void k36(
    const unsigned long long* __restrict__ best_key,
    const unsigned long long* __restrict__ gkey_part, const int* __restrict__ gtl,
    unsigned long long* __restrict__ pos_key,
    int* __restrict__ pos_cnt, int* __restrict__ g_npos,
    int* __restrict__ act_list, int* __restrict__ act_cnt,
    const float* __restrict__ coeffs,
    int* __restrict__ sel_g, _Float16* __restrict__ sel_coef,
    int* __restrict__ sel_cnt, int* __restrict__ done_ctr) {
#pragma clang fp contract(off)
    int b = blockIdx.x;
    int tid = threadIdx.x;
    int lane = tid & 63, wid = tid >> 6;
    __shared__ short s_ov[AA];                  // override g per anchor, -1 none
    __shared__ short s_gi[AA];                  // matched g per anchor
    __shared__ unsigned long long s_gmax[GG];
    __shared__ int sba[GG];
    __shared__ int s_gtl[GG];
    __shared__ unsigned long long s_pmask[NWCH];
    __shared__ unsigned long long s_nmask[NWCH];
    __shared__ int s_woff[NWCH];
    __shared__ int s_wred[5];
    __shared__ int s_cnt, s_act;
    __shared__ int s_hist[256];
    __shared__ int s_sfx[256];
    __shared__ int s_wsum[4];
    __shared__ unsigned long long s_prefix;
    __shared__ int s_kk;
    __shared__ int s_nsel;
    __shared__ int s_sel_a[KPOS];
    __shared__ int s_sorted_a[KPOS];
    __shared__ int s_sorted_g[KPOS];
    __shared__ int s_gcnt[GG];

    for (int i = tid; i < AA; i += 1024) s_ov[i] = -1;
    if (tid < GG) { s_gmax[tid] = 0ULL; s_gtl[tid] = gtl[b * GG + tid]; }
    if (tid == 0) {
        s_cnt = 0; s_act = 0; s_prefix = 0ULL; s_kk = KPOS; s_nsel = 0;
        if (b == 0) *done_ctr = 0;               // reset k457 completion counter
    }
    __syncthreads();
    // reduce 76 per-block partial keys per g (32 g x 32 groups)
    for (int c = tid >> 5; c < NB1; c += 32)
        atomicMax(&s_gmax[tid & 31],
                  gkey_part[((size_t)b * NB1 + c) * GG + (tid & 31)]);
    __syncthreads();
    if (tid < GG) sba[tid] = AA - 1 - (int)(unsigned)(s_gmax[tid] & 0xffffffffULL);
    __syncthreads();
    if (tid == 0) {
        for (int g = 0; g < GG; ++g) s_ov[sba[g]] = (short)g;  // ascending: last wins
    }
    __syncthreads();

    // ---- pass 1: decisions (from packed best_key) + pos keys + ballots ----
    for (int base = 0; base < AA; base += 1024) {
        int a = base + tid;
        bool p = false, npre = false;
        if (a < AA) {
            unsigned long long bk = best_key[(size_t)b * AA + a];
            float biou = __uint_as_float((unsigned)(bk >> 6));
            int bg = (GG - 1) - (int)(bk & 63ULL);
            int ov = s_ov[a];
            int gi = (ov >= 0) ? ov : bg;
            p = (biou >= 0.5f) || (ov >= 0);
            npre = (biou < 0.4f) && !p;
            s_gi[a] = (short)gi;
            if (p) {
                int slot = atomicAdd(&s_cnt, 1);
                unsigned vb = __float_as_uint(biou + 1.0f);   // >= 0x3F800000
                unsigned long long key =
                    ((unsigned long long)(vb - 0x3F800000u) << 32) |
                    (unsigned)(AA - 1 - a);
                pos_key[(size_t)b * AA + slot] = key;
            }
        }
        unsigned long long pm = __ballot(p);
        unsigned long long nm = __ballot(npre);
        if (lane == 0) {
            int w = (base >> 6) + wid;
            s_pmask[w] = pm;
            s_nmask[w] = nm;
        }
    }
    __syncthreads();
    int npos = s_cnt;
    if (tid == 0) { pos_cnt[b] = npos; atomicAdd(g_npos, npos); }
    int cap = npos * NEGRATIO;

    // scan 304 chunk counts with 5 waves
    int c = (tid < NWCH) ? __popcll(s_nmask[tid]) : 0;
    int inc = c;
    if (wid < 5) {
        #pragma unroll
        for (int d = 1; d < 64; d <<= 1) {
            int t = __shfl_up(inc, d);
            if (lane >= d) inc += t;
        }
        if (lane == 63) s_wred[wid] = inc;
    }
    __syncthreads();
    if (tid == 0) {
        int run = 0;
        #pragma unroll
        for (int i = 0; i < 5; ++i) { int t = s_wred[i]; s_wred[i] = run; run += t; }
    }
    __syncthreads();
    if (tid < NWCH) s_woff[tid] = inc - c + s_wred[wid];   // exclusive prefix
    __syncthreads();

    // ---- pass 2: drop negs beyond cap, compact PACKED active rows ----
    for (int base = 0; base < AA; base += 1024) {
        int a = base + tid;
        int w = (base >> 6) + wid;
        unsigned long long nm = s_nmask[w], pm = s_pmask[w];
        bool npre = (nm >> lane) & 1ULL;
        bool pos  = (pm >> lane) & 1ULL;
        int rank = __popcll(nm & ((1ULL << lane) - 1ULL));
        bool kept = npre && (s_woff[w] + rank + 1 <= cap);
        if (a < AA && (pos || kept)) {
            int slot = atomicAdd(&s_act, 1);
            int gi = s_gi[a];
            int lbl = pos ? s_gtl[gi] : 0;
            unsigned e = (unsigned)a | ((unsigned)gi << 15) |
                         ((unsigned)lbl << 20) | (pos ? 0x80000000u : 0u);
            act_list[b * AA + slot] = (int)e;
        }
    }
    __syncthreads();
    if (tid == 0) act_cnt[b] = s_act;

    // ================= k6 phase (same block, same image) =================
    int n = npos;
    int K = (n < KPOS) ? n : KPOS;
    const unsigned long long* keys = pos_key + (size_t)b * AA;  // L1/L2-hot
    __syncthreads();

    if (n > KPOS) {
        for (int d = 6; d >= 0; --d) {
            unsigned long long pref = s_prefix;   // snapshot (post-barrier)
            int kk = s_kk;
            if (tid < 256) s_hist[tid] = 0;
            __syncthreads();
            unsigned long long mhi = ~((1ULL << (8 * (d + 1))) - 1ULL);
            for (int i = tid; i < n; i += 1024) {
                unsigned long long k = keys[i];
                if ((k & mhi) == pref)
                    atomicAdd(&s_hist[(int)((k >> (8 * d)) & 255)], 1);
            }
            __syncthreads();
            int x = 0;
            if (tid < 256) {
                x = s_hist[255 - tid];
                #pragma unroll
                for (int o = 1; o < 64; o <<= 1) {
                    int t = __shfl_up(x, o);
                    if (lane >= o) x += t;
                }
                if (lane == 63) s_wsum[tid >> 6] = x;
            }
            __syncthreads();
            if (tid == 0) {
                int run = 0;
                #pragma unroll
                for (int i = 0; i < 4; ++i) { int t = s_wsum[i]; s_wsum[i] = run; run += t; }
            }
            __syncthreads();
            if (tid < 256) s_sfx[255 - tid] = x + s_wsum[tid >> 6];
            __syncthreads();
            if (tid < 256) {
                int v = tid;
                int ge = s_sfx[v];
                int gt = (v == 255) ? 0 : s_sfx[v + 1];
                if (ge >= kk && gt < kk) {
                    s_prefix = pref | ((unsigned long long)v << (8 * d));
                    s_kk = kk - gt;
                }
            }
            __syncthreads();
        }
    }

    unsigned long long T = (n > KPOS) ? s_prefix : 0ULL;
    for (int i = tid; i < n; i += 1024) {
        unsigned long long k = keys[i];
        if (k >= T) {
            int slot = atomicAdd(&s_nsel, 1);
            if (slot < KPOS)
                s_sel_a[slot] = AA - 1 - (int)(unsigned)(k & 0xffffffffu);
        }
    }
    __syncthreads();

    if (tid < GG) s_gcnt[tid] = 0;
    __syncthreads();
    int mya = -1, myg = -1;
    if (tid < K) {
        mya = s_sel_a[tid];
        myg = s_gi[mya];
        atomicAdd(&s_gcnt[myg], 1);
    }
    __syncthreads();
    if (tid == 0) {
        int run = 0;
        for (int g = 0; g < GG; ++g) { int cg = s_gcnt[g]; s_gcnt[g] = run; run += cg; }
    }
    __syncthreads();
    if (tid < K) {
        int pos = atomicAdd(&s_gcnt[myg], 1);
        s_sorted_a[pos] = mya;
        s_sorted_g[pos] = myg;
    }
    __syncthreads();

    if (tid == 0) sel_cnt[b] = K;
    int glast = (K > 0) ? s_sorted_g[K - 1] : 0;
    for (int t = tid; t < KPOS * PP; t += 1024) {
        int k = t >> 5, p = t & 31;
        _Float16 v = (_Float16)0.0f;
        if (k < K) {
            int a = s_sorted_a[k];
            v = (_Float16)coeffs[((size_t)(b * AA + a)) * PP + p];
        }
        sel_coef[(size_t)(b * KPOS + k) * PP + p] = v;
    }
    for (int t = tid; t < KPOS; t += 1024)
        sel_g[b * KPOS + t] = (t < K) ? s_sorted_g[t] : glast;
}

// ---------------------------------------------------------------------------
// K457: FUSED k45 (focal+box) + k7 (MFMA mask loss) + FINAL REDUCTION.
// The block drawing the last done-ticket (fence + atomicAdd) reduces all
// per-block partials and writes the scalar output — no 5th dispatch.
// ---------------------------------------------------------------------------
__global__ __launch_bounds__(256) void k457(
    const float* __restrict__ cls_p, const int* __restrict__ act_list,
    const int* __restrict__ act_cnt, const float* __restrict__ box_p,
    const float* __restrict__ anchors, const float* __restrict__ gt_boxes,
    float* __restrict__ part_cls, float* __restrict__ part_box,
    const _Float16* __restrict__ protoT, const unsigned* __restrict__ pmask,
    const _Float16* __restrict__ sel_coef, const int* __restrict__ sel_g,
    const int* __restrict__ sel_cnt, float* __restrict__ part_mask,
    const int* __restrict__ npos, int* __restrict__ done_ctr,
    float* __restrict__ out) {
    int b = blockIdx.y;
    int tid = threadIdx.x;
    __shared__ float s4f[4], s4b[4];
    __shared__ int s_last;

    if (blockIdx.x < NB45) {
        // ---- k45 role ----
        int n = act_cnt[b];
        float fsum = 0.0f, bsum = 0.0f;
        for (int i = blockIdx.x * 256 + tid; i < n; i += NB45 * 256) {
            unsigned e = (unsigned)act_list[b * AA + i];
            int a = e & 0x7fff;
            int g = (e >> 15) & 31;
            int lbl = (e >> 20) & 127;
            bool pos = (e >> 31) != 0u;
            const float* x = cls_p + (size_t)(b * AA + a) * CC;
            float v80 = x[80];
            float m0 = v80, m1 = -3.0e38f, m2 = -3.0e38f, m3 = -3.0e38f;
            #pragma unroll
            for (int q = 0; q < 20; ++q) {
                m0 = fmaxf(m0, x[4 * q + 0]); m1 = fmaxf(m1, x[4 * q + 1]);
                m2 = fmaxf(m2, x[4 * q + 2]); m3 = fmaxf(m3, x[4 * q + 3]);
            }
            float m = fmaxf(fmaxf(m0, m1), fmaxf(m2, m3));
            float s0 = __expf(v80 - m), s1 = 0.f, s2 = 0.f, s3 = 0.f;
            #pragma unroll
            for (int q = 0; q < 20; ++q) {
                s0 += __expf(x[4 * q + 0] - m); s1 += __expf(x[4 * q + 1] - m);
                s2 += __expf(x[4 * q + 2] - m); s3 += __expf(x[4 * q + 3] - m);
            }
            float s = (s0 + s1) + (s2 + s3);
            float pt = __expf(x[lbl] - m) / s;
            pt = fminf(fmaxf(pt, 1e-6f), 1.0f - 1e-6f);
            float at = (lbl > 0) ? 0.25f : 0.75f;
            float om = 1.0f - pt;
            fsum += at * om * om * (-__logf(pt));
            if (pos) {
#pragma clang fp contract(off)
                float4 mb = ((const float4*)gt_boxes)[b * GG + g];
                float4 an = ((const float4*)anchors)[a];
                const float4 bp = ((const float4*)box_p)[(size_t)b * AA + a];
                float q0 = mb.x / 550.0f, q1 = mb.y / 550.0f;
                float q2 = mb.z / 550.0f, q3 = mb.w / 550.0f;
                float gcx = 0.5f * (q0 + q2), gcy = 0.5f * (q1 + q3);
                float gw = fmaxf(q2 - q0, 1e-6f), gh = fmaxf(q3 - q1, 1e-6f);
                float t0 = (gcx - an.x) / (an.z * 0.1f);
                float t1 = (gcy - an.y) / (an.w * 0.1f);
                float t2 = logf(gw / an.z) / 0.2f;
                float t3 = logf(gh / an.w) / 0.2f;
                float d;
                d = fabsf(bp.x - t0); bsum += (d < 1.0f) ? 0.5f * d * d : d - 0.5f;
                d = fabsf(bp.y - t1); bsum += (d < 1.0f) ? 0.5f * d * d : d - 0.5f;
                d = fabsf(bp.z - t2); bsum += (d < 1.0f) ? 0.5f * d * d : d - 0.5f;
                d = fabsf(bp.w - t3); bsum += (d < 1.0f) ? 0.5f * d * d : d - 0.5f;
            }
        }
        for (int off = 32; off; off >>= 1) {
            fsum += __shfl_xor(fsum, off);
            bsum += __shfl_xor(bsum, off);
        }
        if ((tid & 63) == 0) { s4f[tid >> 6] = fsum; s4b[tid >> 6] = bsum; }
        __syncthreads();
        if (tid == 0) {
            part_cls[b * NB45 + blockIdx.x] = s4f[0] + s4f[1] + s4f[2] + s4f[3];
            part_box[b * NB45 + blockIdx.x] = s4b[0] + s4b[1] + s4b[2] + s4b[3];
        }
    } else {
        // ---- k7 role ----
        int nk = sel_cnt[b];
        int wave = tid >> 6, lane = tid & 63;
        int lg = lane >> 4;                       // lane group 0..3
        int ln = lane & 15;                       // n (px) / A-row (k) index
        int pt = (blockIdx.x - NB45) * 4 + wave;  // pixel-tile index
        int px = pt * 16 + ln;
        bool pxv = (pt < NPT) && (px < PHW);
        int pc = pxv ? px : PHW - 1;

        half8 bfrag = *(const half8*)&protoT[((size_t)b * PHW + pc) * PP + lg * 8];
        unsigned gmask = pmask[(size_t)b * PHW + pc];

        const _Float16* ca = sel_coef + (size_t)b * KPOS * PP;
        const int* gb = sel_g + b * KPOS;

        half8 af[8];
        int4 gv[8];
        #pragma unroll
        for (int kt = 0; kt < 8; ++kt) {
            af[kt] = *(const half8*)&ca[(size_t)(kt * 16 + ln) * PP + lg * 8];
            gv[kt] = *(const int4*)&gb[kt * 16 + lg * 4];
        }

        float acc = 0.0f;
        #pragma unroll
        for (int kt = 0; kt < 8; ++kt) {
            floatx4 c = {0.f, 0.f, 0.f, 0.f};
            c = __builtin_amdgcn_mfma_f32_16x16x32_f16(af[kt], bfrag, c, 0, 0, 0);
            #pragma unroll
            for (int r = 0; r < 4; ++r) {
                int k = kt * 16 + lg * 4 + r;
                float l = c[r];
                int g0 = (r == 0) ? gv[kt].x : (r == 1) ? gv[kt].y
                       : (r == 2) ? gv[kt].z : gv[kt].w;
                float t = (float)((gmask >> g0) & 1u);
                float bce = fmaxf(l, 0.f) - l * t + __logf(1.f + __expf(-fabsf(l)));
                if (pxv && k < nk) acc += bce;
            }
        }

        for (int off = 32; off; off >>= 1) acc += __shfl_xor(acc, off);
        if (lane == 0) s4f[wave] = acc;
        __syncthreads();
        if (tid == 0)
            part_mask[(size_t)b * NB7 + (blockIdx.x - NB45)] =
                s4f[0] + s4f[1] + s4f[2] + s4f[3];
    }

    // ---- completion ticket; last block reduces everything ----
    if (tid == 0) {
        __threadfence();
        int t = atomicAdd(done_ctr, 1);
        s_last = (t == NTOT - 1) ? 1 : 0;
    }
    __syncthreads();
    if (!s_last) return;
    __threadfence();

    float c = 0.f, bx = 0.f, mk = 0.f;
    for (int i = tid; i < NB45 * BB; i += 256) {
        c += part_cls[i];
        bx += part_box[i];
    }
    for (int i = tid; i < NB7 * BB; i += 256)
        mk += part_mask[i];
    for (int off = 32; off; off >>= 1) {
        c += __shfl_xor(c, off);
        bx += __shfl_xor(bx, off);
        mk += __shfl_xor(mk, off);
    }
    __shared__ float rc[4], rb[4], rm[4];
    if ((tid & 63) == 0) { rc[tid >> 6] = c; rb[tid >> 6] = bx; rm[tid >> 6] = mk; }
    __syncthreads();
    if (tid == 0) {
        float tc = rc[0] + rc[1] + rc[2] + rc[3];
        float tb = rb[0] + rb[1] + rb[2] + rb[3];
        float tm = rm[0] + rm[1] + rm[2] + rm[3];
        float denom = fmaxf((float)(*npos), 1.0f);
        out[0] = (1.0f * tc + 1.5f * tb + 6.125f * (tm / (float)PHW)) / denom;
    }
}

// ---------------------------------------------------------------------------
extern "C" void kernel_launch(void* const* d_in, const int* in_sizes, int n_in,
                              void* d_out, int out_size, void* d_ws, size_t ws_size,
                              hipStream_t stream) {
    (void)in_sizes; (void)n_in; (void)out_size; (void)ws_size;
    const float* class_preds = (const float*)d_in[0];
    const float* box_preds   = (const float*)d_in[1];
    const float* mask_coeffs = (const float*)d_in[2];
    const float* prototypes  = (const float*)d_in[3];
    const float* anchors     = (const float*)d_in[4];
    const float* gt_boxes    = (const float*)d_in[5];
    const int*   gt_labels   = (const int*)d_in[6];
    const float* gt_masks    = (const float*)d_in[7];
    float* out = (float*)d_out;

    size_t off = 0;
    char* w = (char*)d_ws;
    auto take = [&](size_t bytes) -> char* {
        char* p = w + off;
        off += (bytes + 255) & ~(size_t)255;
        return p;
    };
    float* acc      = (float*)take(32);                       // [.,.,., npos(int)]
    int*   done_ctr = (int*)  take(256);
    unsigned long long* best_key =
        (unsigned long long*)take((size_t)BB * AA * 8);
    unsigned long long* gkey_part =
        (unsigned long long*)take((size_t)BB * NB1 * GG * 8);
    int*   pos_cnt  = (int*)  take((size_t)BB * 4);
    unsigned long long* pos_key = (unsigned long long*)take((size_t)BB * AA * 8);
    int*   sel_g    = (int*)  take((size_t)BB * KPOS * 4);
    int*   sel_cnt  = (int*)  take((size_t)BB * 4);
    _Float16* sel_coef = (_Float16*)take((size_t)BB * KPOS * PP * 2);
    int*   act_list = (int*)  take((size_t)BB * AA * 4);
    int*   act_cnt  = (int*)  take((size_t)BB * 4);
    _Float16* protoT = (_Float16*)take((size_t)BB * PHW * PP * 2);
    unsigned* pmaskb = (unsigned*)take((size_t)BB * PHW * 4);
    float* part_cls  = (float*)take((size_t)BB * NB45 * 4);
    float* part_box  = (float*)take((size_t)BB * NB45 * 4);
    float* part_mask = (float*)take((size_t)BB * NB7 * 4);

    k01<<<dim3(NB1 + NB0, BB), 256, 0, stream>>>(
        anchors, gt_boxes, prototypes, gt_masks,
        best_key, gkey_part, acc, protoT, pmaskb);
    k36<<<BB, 1024, 0, stream>>>(
        best_key, gkey_part, gt_labels, pos_key, pos_cnt, (int*)(acc + 3),
        act_list, act_cnt, mask_coeffs, sel_g, sel_coef, sel_cnt, done_ctr);
    k457<<<dim3(NB45 + NB7, BB), 256, 0, stream>>>(
        class_preds, act_list, act_cnt, box_preds, anchors, gt_boxes,
        part_cls, part_box,
        protoT, pmaskb, sel_coef, sel_g, sel_cnt, part_mask,
        (int*)(acc + 3), done_ctr, out);
}

// Round 19
// 67.111 us; speedup vs baseline: 1.8582x; 1.8582x over previous
//
#include <hip/hip_runtime.h>
#include <math.h>

#define BB 8
#define AA 19248
#define GG 32
#define CC 81
#define PP 32
#define PHW 19044   /* 138*138 */
#define KPOS 128
#define NEGRATIO 3
#define NWCH 304    /* 19 outer iters x 16 waves of 64 anchors */
#define NB1 76      /* match-role blocks per image = ceil(AA/256) */
#define NB0 75      /* prep-role blocks per image = ceil(PHW/256) */
#define NPT 1191    /* pixel tiles of 16 = ceil(PHW/16) */
#define NB7 298     /* k7-role blocks per image = ceil(NPT/4) */
#define NB45 24     /* k45-role blocks per image (256 threads each) */

typedef _Float16 half8 __attribute__((ext_vector_type(8)));
typedef float floatx4 __attribute__((ext_vector_type(4)));

// ---------------------------------------------------------------------------
// IoU helper — contraction off so every recomputation produces bitwise-
// identical values and FMA fusion can't flip threshold/argmax decisions.
// ---------------------------------------------------------------------------
__device__ __forceinline__ float iou_one(float ax1, float ay1, float ax2, float ay2,
                                         float areaA,
                                         float gx1, float gy1, float gx2, float gy2) {
#pragma clang fp contract(off)
    float ix1 = fmaxf(ax1, gx1), iy1 = fmaxf(ay1, gy1);
    float ix2 = fminf(ax2, gx2), iy2 = fminf(ay2, gy2);
    float iw = fmaxf(ix2 - ix1, 0.0f), ih = fmaxf(iy2 - iy1, 0.0f);
    float inter = iw * ih;
    float areaB = (gx2 - gx1) * (gy2 - gy1);
    float u = areaA + areaB - inter;
    u = fmaxf(u, 1e-6f);
    return inter / u;
}

// ---------------------------------------------------------------------------
// K01: FUSED prep + match.
//   blockIdx.x <  NB1 : match role — best_key[b][a] = (iou_bits<<6)|(31-g)
//                       (single u64 carries both outputs) + per-(b,g)
//                       best-anchor partial keys.
//   blockIdx.x >= NB1 : prep role — pack binary gt-masks into u32 +
//                       transpose protos to [b][px][32] f16.
// ---------------------------------------------------------------------------
__global__ __launch_bounds__(256) void k01(
    const float* __restrict__ anchors, const float* __restrict__ gt_boxes,
    const float* __restrict__ protos, const float* __restrict__ gtm,
    unsigned long long* __restrict__ best_key,
    unsigned long long* __restrict__ gkey_part, float* __restrict__ acc,
    _Float16* __restrict__ protoT, unsigned* __restrict__ pmask) {
#pragma clang fp contract(off)
    int b = blockIdx.y;
    __shared__ float sg[GG][4];
    __shared__ unsigned long long s_gk[GG];

    if (blockIdx.x >= NB1) {
        // ---- prep role ----
        int px = (blockIdx.x - NB1) * 256 + threadIdx.x;
        if (px >= PHW) return;
        const float* pb = protos + (size_t)b * PP * PHW + px;
        _Float16 v[PP];
        #pragma unroll
        for (int k = 0; k < PP; ++k)
            v[k] = (_Float16)pb[(size_t)k * PHW];
        half8* dst = (half8*)&protoT[((size_t)b * PHW + px) * PP];
        #pragma unroll
        for (int q = 0; q < 4; ++q)
            dst[q] = *(half8*)&v[q * 8];
        const float* gb = gtm + (size_t)b * GG * PHW + px;
        unsigned m = 0u;
        #pragma unroll
        for (int g = 0; g < GG; ++g)
            m |= (gb[(size_t)g * PHW] > 0.5f) ? (1u << g) : 0u;
        pmask[(size_t)b * PHW + px] = m;
        return;
    }

    // ---- match role ----
    int a = blockIdx.x * 256 + threadIdx.x;
    int lane = threadIdx.x & 63;
    if (blockIdx.x == 0 && b == 0 && threadIdx.x < 4)
        ((int*)acc)[threadIdx.x] = 0;            // zero [., ., ., npos]
    for (int t = threadIdx.x; t < GG * 4; t += 256)
        sg[t >> 2][t & 3] = gt_boxes[b * GG * 4 + t] / 550.0f;
    if (threadIdx.x < GG) s_gk[threadIdx.x] = 0ULL;
    __syncthreads();
    bool valid = a < AA;
    int ac = valid ? a : AA - 1;
    float4 an = ((const float4*)anchors)[ac];
    float ax1 = an.x - an.z * 0.5f, ay1 = an.y - an.w * 0.5f;
    float ax2 = an.x + an.z * 0.5f, ay2 = an.y + an.w * 0.5f;
    float areaA = (ax2 - ax1) * (ay2 - ay1);
    unsigned long long bk = 0ULL;   // (vbits<<6)|(31-g): max => first-max argmax
    for (int gg = 0; gg < GG; ++gg) {
        int g = (gg + lane) & (GG - 1);          // stagger: 32 distinct LDS slots
        float v = iou_one(ax1, ay1, ax2, ay2, areaA, sg[g][0], sg[g][1], sg[g][2], sg[g][3]);
        unsigned vb = __float_as_uint(v);        // v >= 0 -> order-preserving
        unsigned long long k2 = ((unsigned long long)vb << 6) | (unsigned)(GG - 1 - g);
        if (k2 > bk) bk = k2;
        if (valid) {
            unsigned long long kg =
                ((unsigned long long)vb << 32) | (unsigned)(AA - 1 - a);
            atomicMax(&s_gk[g], kg);
        }
    }
    if (valid) best_key[(size_t)b * AA + a] = bk;
    __syncthreads();
    if (threadIdx.x < GG)
        gkey_part[((size_t)b * NB1 + blockIdx.x) * GG + threadIdx.x] = s_gk[threadIdx.x];
}

// ---------------------------------------------------------------------------
// K36: FUSED k3 (match-scan) + k6 (top-K radix select), one block per image.
// All per-anchor state (override g, matched g) lives in LDS; the only global
// side products are pos_key (consumed in-block, L1/L2-hot), act_list
// (packed a|g<<15|lbl<<20|pos<<31), counts, and the f16 coeff + sel_g
// tables for K7.
// ---------------------------------------------------------------------------
__global__ __launch_bounds__(1024) void k36(
    const unsigned long long* __restrict__ best_key,
    const unsigned long long* __restrict__ gkey_part, const int* __restrict__ gtl,
    unsigned long long* __restrict__ pos_key,
    int* __restrict__ pos_cnt, int* __restrict__ g_npos,
    int* __restrict__ act_list, int* __restrict__ act_cnt,
    const float* __restrict__ coeffs,
    int* __restrict__ sel_g, _Float16* __restrict__ sel_coef,
    int* __restrict__ sel_cnt) {
#pragma clang fp contract(off)
    int b = blockIdx.x;
    int tid = threadIdx.x;
    int lane = tid & 63, wid = tid >> 6;
    __shared__ short s_ov[AA];                  // override g per anchor, -1 none
    __shared__ short s_gi[AA];                  // matched g per anchor
    __shared__ unsigned long long s_gmax[GG];
    __shared__ int sba[GG];
    __shared__ int s_gtl[GG];
    __shared__ unsigned long long s_pmask[NWCH];
    __shared__ unsigned long long s_nmask[NWCH];
    __shared__ int s_woff[NWCH];
    __shared__ int s_wred[5];
    __shared__ int s_cnt, s_act;
    __shared__ int s_hist[256];
    __shared__ int s_sfx[256];
    __shared__ int s_wsum[4];
    __shared__ unsigned long long s_prefix;
    __shared__ int s_kk;
    __shared__ int s_nsel;
    __shared__ int s_sel_a[KPOS];
    __shared__ int s_sorted_a[KPOS];
    __shared__ int s_sorted_g[KPOS];
    __shared__ int s_gcnt[GG];

    for (int i = tid; i < AA; i += 1024) s_ov[i] = -1;
    if (tid < GG) { s_gmax[tid] = 0ULL; s_gtl[tid] = gtl[b * GG + tid]; }
    if (tid == 0) { s_cnt = 0; s_act = 0; s_prefix = 0ULL; s_kk = KPOS; s_nsel = 0; }
    __syncthreads();
    // reduce 76 per-block partial keys per g (32 g x 32 groups)
    for (int c = tid >> 5; c < NB1; c += 32)
        atomicMax(&s_gmax[tid & 31],
                  gkey_part[((size_t)b * NB1 + c) * GG + (tid & 31)]);
    __syncthreads();
    if (tid < GG) sba[tid] = AA - 1 - (int)(unsigned)(s_gmax[tid] & 0xffffffffULL);
    __syncthreads();
    if (tid == 0) {
        for (int g = 0; g < GG; ++g) s_ov[sba[g]] = (short)g;  // ascending: last wins
    }
    __syncthreads();

    // ---- pass 1: decisions (from packed best_key) + pos keys + ballots ----
    for (int base = 0; base < AA; base += 1024) {
        int a = base + tid;
        bool p = false, npre = false;
        if (a < AA) {
            unsigned long long bk = best_key[(size_t)b * AA + a];
            float biou = __uint_as_float((unsigned)(bk >> 6));
            int bg = (GG - 1) - (int)(bk & 63ULL);
            int ov = s_ov[a];
            int gi = (ov >= 0) ? ov : bg;
            p = (biou >= 0.5f) || (ov >= 0);
            npre = (biou < 0.4f) && !p;
            s_gi[a] = (short)gi;
            if (p) {
                int slot = atomicAdd(&s_cnt, 1);
                unsigned vb = __float_as_uint(biou + 1.0f);   // >= 0x3F800000
                unsigned long long key =
                    ((unsigned long long)(vb - 0x3F800000u) << 32) |
                    (unsigned)(AA - 1 - a);
                pos_key[(size_t)b * AA + slot] = key;
            }
        }
        unsigned long long pm = __ballot(p);
        unsigned long long nm = __ballot(npre);
        if (lane == 0) {
            int w = (base >> 6) + wid;
            s_pmask[w] = pm;
            s_nmask[w] = nm;
        }
    }
    __syncthreads();
    int npos = s_cnt;
    if (tid == 0) { pos_cnt[b] = npos; atomicAdd(g_npos, npos); }
    int cap = npos * NEGRATIO;

    // scan 304 chunk counts with 5 waves
    int c = (tid < NWCH) ? __popcll(s_nmask[tid]) : 0;
    int inc = c;
    if (wid < 5) {
        #pragma unroll
        for (int d = 1; d < 64; d <<= 1) {
            int t = __shfl_up(inc, d);
            if (lane >= d) inc += t;
        }
        if (lane == 63) s_wred[wid] = inc;
    }
    __syncthreads();
    if (tid == 0) {
        int run = 0;
        #pragma unroll
        for (int i = 0; i < 5; ++i) { int t = s_wred[i]; s_wred[i] = run; run += t; }
    }
    __syncthreads();
    if (tid < NWCH) s_woff[tid] = inc - c + s_wred[wid];   // exclusive prefix
    __syncthreads();

    // ---- pass 2: drop negs beyond cap, compact PACKED active rows ----
    for (int base = 0; base < AA; base += 1024) {
        int a = base + tid;
        int w = (base >> 6) + wid;
        unsigned long long nm = s_nmask[w], pm = s_pmask[w];
        bool npre = (nm >> lane) & 1ULL;
        bool pos  = (pm >> lane) & 1ULL;
        int rank = __popcll(nm & ((1ULL << lane) - 1ULL));
        bool kept = npre && (s_woff[w] + rank + 1 <= cap);
        if (a < AA && (pos || kept)) {
            int slot = atomicAdd(&s_act, 1);
            int gi = s_gi[a];
            int lbl = pos ? s_gtl[gi] : 0;
            unsigned e = (unsigned)a | ((unsigned)gi << 15) |
                         ((unsigned)lbl << 20) | (pos ? 0x80000000u : 0u);
            act_list[b * AA + slot] = (int)e;
        }
    }
    __syncthreads();
    if (tid == 0) act_cnt[b] = s_act;

    // ================= k6 phase (same block, same image) =================
    int n = npos;
    int K = (n < KPOS) ? n : KPOS;
    const unsigned long long* keys = pos_key + (size_t)b * AA;  // L1/L2-hot
    __syncthreads();

    if (n > KPOS) {
        for (int d = 6; d >= 0; --d) {
            unsigned long long pref = s_prefix;   // snapshot (post-barrier)
            int kk = s_kk;
            if (tid < 256) s_hist[tid] = 0;
            __syncthreads();
            unsigned long long mhi = ~((1ULL << (8 * (d + 1))) - 1ULL);
            for (int i = tid; i < n; i += 1024) {
                unsigned long long k = keys[i];
                if ((k & mhi) == pref)
                    atomicAdd(&s_hist[(int)((k >> (8 * d)) & 255)], 1);
            }
            __syncthreads();
            int x = 0;
            if (tid < 256) {
                x = s_hist[255 - tid];
                #pragma unroll
                for (int o = 1; o < 64; o <<= 1) {
                    int t = __shfl_up(x, o);
                    if (lane >= o) x += t;
                }
                if (lane == 63) s_wsum[tid >> 6] = x;
            }
            __syncthreads();
            if (tid == 0) {
                int run = 0;
                #pragma unroll
                for (int i = 0; i < 4; ++i) { int t = s_wsum[i]; s_wsum[i] = run; run += t; }
            }
            __syncthreads();
            if (tid < 256) s_sfx[255 - tid] = x + s_wsum[tid >> 6];
            __syncthreads();
            if (tid < 256) {
                int v = tid;
                int ge = s_sfx[v];
                int gt = (v == 255) ? 0 : s_sfx[v + 1];
                if (ge >= kk && gt < kk) {
                    s_prefix = pref | ((unsigned long long)v << (8 * d));
                    s_kk = kk - gt;
                }
            }
            __syncthreads();
        }
    }

    unsigned long long T = (n > KPOS) ? s_prefix : 0ULL;
    for (int i = tid; i < n; i += 1024) {
        unsigned long long k = keys[i];
        if (k >= T) {
            int slot = atomicAdd(&s_nsel, 1);
            if (slot < KPOS)
                s_sel_a[slot] = AA - 1 - (int)(unsigned)(k & 0xffffffffu);
        }
    }
    __syncthreads();

    if (tid < GG) s_gcnt[tid] = 0;
    __syncthreads();
    int mya = -1, myg = -1;
    if (tid < K) {
        mya = s_sel_a[tid];
        myg = s_gi[mya];
        atomicAdd(&s_gcnt[myg], 1);
    }
    __syncthreads();
    if (tid == 0) {
        int run = 0;
        for (int g = 0; g < GG; ++g) { int cg = s_gcnt[g]; s_gcnt[g] = run; run += cg; }
    }
    __syncthreads();
    if (tid < K) {
        int pos = atomicAdd(&s_gcnt[myg], 1);
        s_sorted_a[pos] = mya;
        s_sorted_g[pos] = myg;
    }
    __syncthreads();

    if (tid == 0) sel_cnt[b] = K;
    int glast = (K > 0) ? s_sorted_g[K - 1] : 0;
    for (int t = tid; t < KPOS * PP; t += 1024) {
        int k = t >> 5, p = t & 31;
        _Float16 v = (_Float16)0.0f;
        if (k < K) {
            int a = s_sorted_a[k];
            v = (_Float16)coeffs[((size_t)(b * AA + a)) * PP + p];
        }
        sel_coef[(size_t)(b * KPOS + k) * PP + p] = v;
    }
    for (int t = tid; t < KPOS; t += 1024)
        sel_g[b * KPOS + t] = (t < K) ? s_sorted_g[t] : glast;
}

// ---------------------------------------------------------------------------
// K457: FUSED k45 (focal+box) + k7 (MFMA mask loss). NO completion ticket —
// round-18 regression: per-block device-scope __threadfence + same-address
// atomic ticket cost ~70 us on MI355X (non-coherent per-XCD L2s make the
// fence a cross-XCD sync). Final reduction stays a separate tiny dispatch.
// ---------------------------------------------------------------------------
__global__ __launch_bounds__(256) void k457(
    const float* __restrict__ cls_p, const int* __restrict__ act_list,
    const int* __restrict__ act_cnt, const float* __restrict__ box_p,
    const float* __restrict__ anchors, const float* __restrict__ gt_boxes,
    float* __restrict__ part_cls, float* __restrict__ part_box,
    const _Float16* __restrict__ protoT, const unsigned* __restrict__ pmask,
    const _Float16* __restrict__ sel_coef, const int* __restrict__ sel_g,
    const int* __restrict__ sel_cnt, float* __restrict__ part_mask) {
    int b = blockIdx.y;
    int tid = threadIdx.x;
    __shared__ float s4f[4], s4b[4];

    if (blockIdx.x < NB45) {
        // ---- k45 role ----
        int n = act_cnt[b];
        float fsum = 0.0f, bsum = 0.0f;
        for (int i = blockIdx.x * 256 + tid; i < n; i += NB45 * 256) {
            unsigned e = (unsigned)act_list[b * AA + i];
            int a = e & 0x7fff;
            int g = (e >> 15) & 31;
            int lbl = (e >> 20) & 127;
            bool pos = (e >> 31) != 0u;
            const float* x = cls_p + (size_t)(b * AA + a) * CC;
            float v80 = x[80];
            float m0 = v80, m1 = -3.0e38f, m2 = -3.0e38f, m3 = -3.0e38f;
            #pragma unroll
            for (int q = 0; q < 20; ++q) {
                m0 = fmaxf(m0, x[4 * q + 0]); m1 = fmaxf(m1, x[4 * q + 1]);
                m2 = fmaxf(m2, x[4 * q + 2]); m3 = fmaxf(m3, x[4 * q + 3]);
            }
            float m = fmaxf(fmaxf(m0, m1), fmaxf(m2, m3));
            float s0 = __expf(v80 - m), s1 = 0.f, s2 = 0.f, s3 = 0.f;
            #pragma unroll
            for (int q = 0; q < 20; ++q) {
                s0 += __expf(x[4 * q + 0] - m); s1 += __expf(x[4 * q + 1] - m);
                s2 += __expf(x[4 * q + 2] - m); s3 += __expf(x[4 * q + 3] - m);
            }
            float s = (s0 + s1) + (s2 + s3);
            float pt = __expf(x[lbl] - m) / s;
            pt = fminf(fmaxf(pt, 1e-6f), 1.0f - 1e-6f);
            float at = (lbl > 0) ? 0.25f : 0.75f;
            float om = 1.0f - pt;
            fsum += at * om * om * (-__logf(pt));
            if (pos) {
#pragma clang fp contract(off)
                float4 mb = ((const float4*)gt_boxes)[b * GG + g];
                float4 an = ((const float4*)anchors)[a];
                const float4 bp = ((const float4*)box_p)[(size_t)b * AA + a];
                float q0 = mb.x / 550.0f, q1 = mb.y / 550.0f;
                float q2 = mb.z / 550.0f, q3 = mb.w / 550.0f;
                float gcx = 0.5f * (q0 + q2), gcy = 0.5f * (q1 + q3);
                float gw = fmaxf(q2 - q0, 1e-6f), gh = fmaxf(q3 - q1, 1e-6f);
                float t0 = (gcx - an.x) / (an.z * 0.1f);
                float t1 = (gcy - an.y) / (an.w * 0.1f);
                float t2 = logf(gw / an.z) / 0.2f;
                float t3 = logf(gh / an.w) / 0.2f;
                float d;
                d = fabsf(bp.x - t0); bsum += (d < 1.0f) ? 0.5f * d * d : d - 0.5f;
                d = fabsf(bp.y - t1); bsum += (d < 1.0f) ? 0.5f * d * d : d - 0.5f;
                d = fabsf(bp.z - t2); bsum += (d < 1.0f) ? 0.5f * d * d : d - 0.5f;
                d = fabsf(bp.w - t3); bsum += (d < 1.0f) ? 0.5f * d * d : d - 0.5f;
            }
        }
        for (int off = 32; off; off >>= 1) {
            fsum += __shfl_xor(fsum, off);
            bsum += __shfl_xor(bsum, off);
        }
        if ((tid & 63) == 0) { s4f[tid >> 6] = fsum; s4b[tid >> 6] = bsum; }
        __syncthreads();
        if (tid == 0) {
            part_cls[b * NB45 + blockIdx.x] = s4f[0] + s4f[1] + s4f[2] + s4f[3];
            part_box[b * NB45 + blockIdx.x] = s4b[0] + s4b[1] + s4b[2] + s4b[3];
        }
        return;
    }

    // ---- k7 role ----
    int nk = sel_cnt[b];
    int wave = tid >> 6, lane = tid & 63;
    int lg = lane >> 4;                       // lane group 0..3
    int ln = lane & 15;                       // n (px) / A-row (k) index
    int pt = (blockIdx.x - NB45) * 4 + wave;  // pixel-tile index
    int px = pt * 16 + ln;
    bool pxv = (pt < NPT) && (px < PHW);
    int pc = pxv ? px : PHW - 1;

    half8 bfrag = *(const half8*)&protoT[((size_t)b * PHW + pc) * PP + lg * 8];
    unsigned gmask = pmask[(size_t)b * PHW + pc];

    const _Float16* ca = sel_coef + (size_t)b * KPOS * PP;
    const int* gb = sel_g + b * KPOS;

    half8 af[8];
    int4 gv[8];
    #pragma unroll
    for (int kt = 0; kt < 8; ++kt) {
        af[kt] = *(const half8*)&ca[(size_t)(kt * 16 + ln) * PP + lg * 8];
        gv[kt] = *(const int4*)&gb[kt * 16 + lg * 4];
    }

    float acc = 0.0f;
    #pragma unroll
    for (int kt = 0; kt < 8; ++kt) {
        floatx4 c = {0.f, 0.f, 0.f, 0.f};
        c = __builtin_amdgcn_mfma_f32_16x16x32_f16(af[kt], bfrag, c, 0, 0, 0);
        #pragma unroll
        for (int r = 0; r < 4; ++r) {
            int k = kt * 16 + lg * 4 + r;
            float l = c[r];
            int g0 = (r == 0) ? gv[kt].x : (r == 1) ? gv[kt].y
                   : (r == 2) ? gv[kt].z : gv[kt].w;
            float t = (float)((gmask >> g0) & 1u);
            float bce = fmaxf(l, 0.f) - l * t + __logf(1.f + __expf(-fabsf(l)));
            if (pxv && k < nk) acc += bce;
        }
    }

    for (int off = 32; off; off >>= 1) acc += __shfl_xor(acc, off);
    if (lane == 0) s4f[wave] = acc;
    __syncthreads();
    if (tid == 0)
        part_mask[(size_t)b * NB7 + (blockIdx.x - NB45)] =
            s4f[0] + s4f[1] + s4f[2] + s4f[3];
}

// ---------------------------------------------------------------------------
// K8: final reduction over all per-block partials (separate tiny dispatch —
// cheaper than any in-kernel grid-wide completion scheme on this chip).
// ---------------------------------------------------------------------------
__global__ __launch_bounds__(1024) void k8_final(
    const float* __restrict__ part_cls, const float* __restrict__ part_box,
    const float* __restrict__ part_mask, const int* __restrict__ npos,
    float* __restrict__ out) {
    int tid = threadIdx.x;
    float c = 0.f, bx = 0.f, mk = 0.f;
    for (int i = tid; i < NB45 * BB; i += 1024) {
        c += part_cls[i];
        bx += part_box[i];
    }
    for (int i = tid; i < NB7 * BB; i += 1024)
        mk += part_mask[i];
    for (int off = 32; off; off >>= 1) {
        c += __shfl_xor(c, off);
        bx += __shfl_xor(bx, off);
        mk += __shfl_xor(mk, off);
    }
    __shared__ float sc[16], sb[16], sm[16];
    if ((tid & 63) == 0) {
        sc[tid >> 6] = c; sb[tid >> 6] = bx; sm[tid >> 6] = mk;
    }
    __syncthreads();
    if (tid == 0) {
        float tc = 0.f, tb = 0.f, tm = 0.f;
        #pragma unroll
        for (int i = 0; i < 16; ++i) { tc += sc[i]; tb += sb[i]; tm += sm[i]; }
        float denom = fmaxf((float)(*npos), 1.0f);
        out[0] = (1.0f * tc + 1.5f * tb + 6.125f * (tm / (float)PHW)) / denom;
    }
}

// ---------------------------------------------------------------------------
extern "C" void kernel_launch(void* const* d_in, const int* in_sizes, int n_in,
                              void* d_out, int out_size, void* d_ws, size_t ws_size,
                              hipStream_t stream) {
    (void)in_sizes; (void)n_in; (void)out_size; (void)ws_size;
    const float* class_preds = (const float*)d_in[0];
    const float* box_preds   = (const float*)d_in[1];
    const float* mask_coeffs = (const float*)d_in[2];
    const float* prototypes  = (const float*)d_in[3];
    const float* anchors     = (const float*)d_in[4];
    const float* gt_boxes    = (const float*)d_in[5];
    const int*   gt_labels   = (const int*)d_in[6];
    const float* gt_masks    = (const float*)d_in[7];
    float* out = (float*)d_out;

    size_t off = 0;
    char* w = (char*)d_ws;
    auto take = [&](size_t bytes) -> char* {
        char* p = w + off;
        off += (bytes + 255) & ~(size_t)255;
        return p;
    };
    float* acc      = (float*)take(32);                       // [.,.,., npos(int)]
    unsigned long long* best_key =
        (unsigned long long*)take((size_t)BB * AA * 8);
    unsigned long long* gkey_part =
        (unsigned long long*)take((size_t)BB * NB1 * GG * 8);
    int*   pos_cnt  = (int*)  take((size_t)BB * 4);
    unsigned long long* pos_key = (unsigned long long*)take((size_t)BB * AA * 8);
    int*   sel_g    = (int*)  take((size_t)BB * KPOS * 4);
    int*   sel_cnt  = (int*)  take((size_t)BB * 4);
    _Float16* sel_coef = (_Float16*)take((size_t)BB * KPOS * PP * 2);
    int*   act_list = (int*)  take((size_t)BB * AA * 4);
    int*   act_cnt  = (int*)  take((size_t)BB * 4);
    _Float16* protoT = (_Float16*)take((size_t)BB * PHW * PP * 2);
    unsigned* pmaskb = (unsigned*)take((size_t)BB * PHW * 4);
    float* part_cls  = (float*)take((size_t)BB * NB45 * 4);
    float* part_box  = (float*)take((size_t)BB * NB45 * 4);
    float* part_mask = (float*)take((size_t)BB * NB7 * 4);

    k01<<<dim3(NB1 + NB0, BB), 256, 0, stream>>>(
        anchors, gt_boxes, prototypes, gt_masks,
        best_key, gkey_part, acc, protoT, pmaskb);
    k36<<<BB, 1024, 0, stream>>>(
        best_key, gkey_part, gt_labels, pos_key, pos_cnt, (int*)(acc + 3),
        act_list, act_cnt, mask_coeffs, sel_g, sel_coef, sel_cnt);
    k457<<<dim3(NB45 + NB7, BB), 256, 0, stream>>>(
        class_preds, act_list, act_cnt, box_preds, anchors, gt_boxes,
        part_cls, part_box,
        protoT, pmaskb, sel_coef, sel_g, sel_cnt, part_mask);
    k8_final<<<1, 1024, 0, stream>>>(
        part_cls, part_box, part_mask, (int*)(acc + 3), out);
}